// Round 20
// baseline (68.539 us; speedup 1.0000x reference)
//
#include <hip/hip_runtime.h>
#include <math.h>

#define DIM 96
#define NE 4
#define HH 128
#define WW 128
#define BB 16
#define KP 24   // u16 per hs row: 48 B
#define HSROW (KP * 2)           // 48 B
#define HSBUF (WW * HSROW)       // 6144 B per sub-buffer

typedef __attribute__((ext_vector_type(8))) __bf16 bf16x8;
typedef __attribute__((ext_vector_type(2))) __bf16 bf16x2;
typedef __attribute__((ext_vector_type(4))) float floatx4;

// 2x f32 -> packed bf16x2 (compiler emits v_cvt_pk_bf16_f32, RNE)
__device__ __forceinline__ unsigned pack2(float a, float b) {
    bf16x2 v;
    v.x = (__bf16)a;
    v.y = (__bf16)b;
    return __builtin_bit_cast(unsigned, v);
}

// lane N <- lane N-1 (shfl_up 1), pure-VALU DPP (wf_shr:1), OOB lanes -> 0
__device__ __forceinline__ float dpp_up1(float v) {
    return __builtin_bit_cast(float, __builtin_amdgcn_mov_dpp(
        __builtin_bit_cast(int, v), 0x138, 0xF, 0xF, true));
}
// lane N <- lane N+1 (shfl_down 1), DPP (wf_shl:1)
__device__ __forceinline__ float dpp_down1(float v) {
    return __builtin_bit_cast(float, __builtin_amdgcn_mov_dpp(
        __builtin_bit_cast(int, v), 0x130, 0xF, 0xF, true));
}

// LDS-only barrier: make ds_writes visible, rendezvous, but do NOT drain
// vmcnt -- in-flight global prefetches survive the barrier (T4 pattern).
__device__ __forceinline__ void barrier_lds_only() {
    asm volatile("s_waitcnt lgkmcnt(0)" ::: "memory");
    __builtin_amdgcn_s_barrier();
}

// exact-erf GELU via Abramowitz-Stegun 7.1.26 (|eps| <= 1.5e-7), branchless
__device__ __forceinline__ float gelu_erf(float h) {
    const float x = h * 0.70710678118654752f;
    const float a = fabsf(x);
    const float t = __builtin_amdgcn_rcpf(__builtin_fmaf(0.3275911f, a, 1.0f));
    float p = __builtin_fmaf(1.061405429f, t, -1.453152027f);
    p = __builtin_fmaf(p, t, 1.421413741f);
    p = __builtin_fmaf(p, t, -0.284496736f);
    p = __builtin_fmaf(p, t, 0.254829592f);
    p *= t;
    const float e = __expf(-x * x);
    float erfv = __builtin_fmaf(-p, e, 1.0f);
    erfv = copysignf(erfv, x);
    return 0.5f * h * (1.0f + erfv);
}

// ---------------- Kernel A: per-(b,c) mean pool ----------------
__global__ __launch_bounds__(256) void pool_kernel(const float* __restrict__ x,
                                                   float* __restrict__ pooled) {
    const int bc = blockIdx.x;
    const float4* p = (const float4*)(x + (size_t)bc * (HH * WW));
    const int t = threadIdx.x;
    float s = 0.f;
#pragma unroll
    for (int k = 0; k < (HH * WW / 4) / 256; ++k) {
        float4 v = p[t + k * 256];
        s += v.x + v.y + v.z + v.w;
    }
#pragma unroll
    for (int off = 32; off; off >>= 1) s += __shfl_down(s, off, 64);
    __shared__ float ls[4];
    if ((t & 63) == 0) ls[t >> 6] = s;
    __syncthreads();
    if (t == 0) pooled[bc] = (ls[0] + ls[1] + ls[2] + ls[3]) * (1.0f / (HH * WW));
}

// issue 6 float4 loads (2 ch x 3 rows) for one 16-ch sub-chunk
__device__ __forceinline__ void issue_sub(const float* __restrict__ x, int b,
                                          int cbase, int cg, int rr0, int r,
                                          int rr2, int p4, float4 f[2][3]) {
#pragma unroll
    for (int u = 0; u < 2; ++u) {
        const float* pl = x + (size_t)(b * DIM + cbase + cg * 2 + u) * (HH * WW);
        f[u][0] = *(const float4*)(pl + rr0 * WW + p4);
        f[u][1] = *(const float4*)(pl + r   * WW + p4);
        f[u][2] = *(const float4*)(pl + rr2 * WW + p4);
    }
}

// depthwise taps + GELU from preloaded registers -> swizzled hs writes
__device__ __forceinline__ void compute_sub(const float4 f[2][3],
                                            const float (*dwc)[12], int cb,
                                            int cg, float lmask, float rmask,
                                            unsigned char* hsbuf, int p4,
                                            unsigned swz) {
    float hq[2][4];
#pragma unroll
    for (int u = 0; u < 2; ++u) {
        const int c = cb + cg * 2 + u;
        const float4 wA = *(const float4*)&dwc[c][0];   // q0..q3
        const float4 wB = *(const float4*)&dwc[c][4];   // q4..q7
        const float4 wC = *(const float4*)&dwc[c][8];   // q8, bias
        float h0 = wC.y, h1 = wC.y, h2 = wC.y, h3 = wC.y;
#pragma unroll
        for (int row = 0; row < 3; ++row) {
            const float ta = (row == 0) ? wA.x : ((row == 1) ? wA.w : wB.z);
            const float tb = (row == 0) ? wA.y : ((row == 1) ? wB.x : wB.w);
            const float tc = (row == 0) ? wA.z : ((row == 1) ? wB.y : wC.x);
            const float4 f4 = f[u][row];
            const float vl = dpp_up1(f4.w) * lmask;    // VALU DPP, no LDS pipe
            const float vr = dpp_down1(f4.x) * rmask;
            h0 = __builtin_fmaf(ta, vl,   __builtin_fmaf(tb, f4.x, __builtin_fmaf(tc, f4.y, h0)));
            h1 = __builtin_fmaf(ta, f4.x, __builtin_fmaf(tb, f4.y, __builtin_fmaf(tc, f4.z, h1)));
            h2 = __builtin_fmaf(ta, f4.y, __builtin_fmaf(tb, f4.z, __builtin_fmaf(tc, f4.w, h2)));
            h3 = __builtin_fmaf(ta, f4.z, __builtin_fmaf(tb, f4.w, __builtin_fmaf(tc, vr, h3)));
        }
        hq[u][0] = gelu_erf(h0);
        hq[u][1] = gelu_erf(h1);
        hq[u][2] = gelu_erf(h2);
        hq[u][3] = gelu_erf(h3);
    }
    const unsigned wb0 = (unsigned)(p4 * HSROW + cg * 4);
#pragma unroll
    for (int j = 0; j < 4; ++j) {
        const unsigned off = (wb0 + (unsigned)j * HSROW) ^ swz;
        *(unsigned*)(hsbuf + off) = pack2(hq[0][j], hq[1][j]);
    }
}

// ---------------- Kernel C: fused router + expert, 1 data barrier ----------
// 256 threads = 4 waves, 1 row per block, 41.5 KB LDS (3 blocks/CU).
// All 6 sub-chunks computed back-to-back into 6 private hs buffers, ONE
// barrier, then all 36 MFMAs. A-fragments direct from global (L2-hot),
// converted mid-shadow into af[3][3] regs. lgkm-only barriers; DPP halo.
__global__ __launch_bounds__(256, 3) void moe_main(
    const float* __restrict__ x, const float* __restrict__ dw_w,
    const float* __restrict__ dw_b, const float* __restrict__ pw_w,
    const float* __restrict__ pw_b, const float* __restrict__ pooled,
    const float* __restrict__ rw, const float* __restrict__ rb,
    float* __restrict__ out) {
    __shared__ __align__(16) unsigned char hsb[6 * HSBUF];     // 36.9 KB
    __shared__ float dwc[DIM][12];                             // 4.6 KB
    __shared__ float lsm[4];                                   // router logits

    const int t = threadIdx.x;
    const unsigned bid = blockIdx.x;      // 0..2047
    const int xcd = bid & 7;
    const int s = bid >> 3;               // 0..255
    const int b = xcd * 2 + (s >> 7);     // 2 images per XCD
    const int r = s & 127;                // rows sequential within XCD

    const int lane = t & 63, w = t >> 6;
    const int wm = w & 1, wn = w >> 1;
    const int ln = lane & 15, kg = lane >> 4;
    const int cobase = wm * 48, pxbase = wn * 64;

    const int g32 = t & 31;        // px group (4 px each)
    const int p4 = g32 * 4;
    const int cg = t >> 5;         // 0..7 channel group (2 ch each)
    const unsigned swz = (unsigned)((g32 & 7) << 4);
    const float lmask = (p4 == 0) ? 0.f : 1.f;
    const float rmask = (p4 == 124) ? 0.f : 1.f;

    const float m0 = (r > 0) ? 1.f : 0.f;
    const float m2 = (r < HH - 1) ? 1.f : 0.f;
    const int rr0 = (r > 0) ? r - 1 : 0;
    const int rr2 = (r < HH - 1) ? r + 1 : HH - 1;

    // prologue: issue pair-0 x prefetch (expert-independent) first
    float4 fA[2][3], fB[2][3];
    issue_sub(x, b, 0, cg, rr0, r, rr2, p4, fA);
    issue_sub(x, b, 16, cg, rr0, r, rr2, p4, fB);

    // ---- fused router: wave w computes expert w's logit
    {
        float part = pooled[b * DIM + lane] * rw[w * DIM + lane];
        if (lane < 32)
            part += pooled[b * DIM + 64 + lane] * rw[w * DIM + 64 + lane];
#pragma unroll
        for (int off = 32; off; off >>= 1) part += __shfl_down(part, off, 64);
        if (lane == 0) lsm[w] = part + rb[w];
    }
    barrier_lds_only();
    int e;
    float g;
    {
        const float l0 = lsm[0], l1 = lsm[1], l2 = lsm[2], l3 = lsm[3];
        float m = l0; int mi = 0;
        if (l1 > m) { m = l1; mi = 1; }
        if (l2 > m) { m = l2; mi = 2; }
        if (l3 > m) { m = l3; mi = 3; }
        const float denom = __expf(l0 - m) + __expf(l1 - m) +
                            __expf(l2 - m) + __expf(l3 - m);
        const float wv = 1.0f / denom;
        g = wv / (wv + 1e-8f);
        e = mi;
    }

    // ---- stage depthwise taps + bias, row-edge masks folded in
    for (int j = t; j < DIM * 12; j += 256) {
        const int c = j / 12, q = j - c * 12;
        float v = 0.f;
        if (q < 9) {
            v = dw_w[((size_t)e * DIM + c) * 9 + q];
            if (q < 3) v *= m0;
            if (q >= 6) v *= m2;
        } else if (q == 9) v = dw_b[e * DIM + c];
        dwc[c][q] = v;
    }
    barrier_lds_only();   // fA/fB prefetches survive

    // ---- compute phase: all 6 subs into 6 private hs buffers, no barriers
    bf16x8 af[3][3];
#pragma unroll
    for (int pair = 0; pair < 3; ++pair) {
        const int cb = pair * 32;
        // issue this pair's A-fragment loads (L2-hot)
        float4 a0[3], a1[3];
#pragma unroll
        for (int mf = 0; mf < 3; ++mf) {
            const float* ap = pw_w + ((size_t)e * DIM + cobase + mf * 16 + ln) * DIM
                              + cb + kg * 8;
            a0[mf] = *(const float4*)ap;
            a1[mf] = *(const float4*)(ap + 4);
        }
        // compute sub0 from in-flight fA, refill fA for next pair
        compute_sub(fA, dwc, cb, cg, lmask, rmask,
                    hsb + (unsigned)(pair * 2) * HSBUF, p4, swz);
        if (pair < 2) issue_sub(x, b, cb + 32, cg, rr0, r, rr2, p4, fA);
        // convert A-fragments mid-shadow: raw a0/a1 die here (short range)
#pragma unroll
        for (int mf = 0; mf < 3; ++mf) {
            uint4 u;
            u.x = pack2(a0[mf].x, a0[mf].y);
            u.y = pack2(a0[mf].z, a0[mf].w);
            u.z = pack2(a1[mf].x, a1[mf].y);
            u.w = pack2(a1[mf].z, a1[mf].w);
            af[pair][mf] = __builtin_bit_cast(bf16x8, u);
        }
        // compute sub1 from in-flight fB, refill fB for next pair
        compute_sub(fB, dwc, cb + 16, cg, lmask, rmask,
                    hsb + (unsigned)(pair * 2 + 1) * HSBUF, p4, swz);
        if (pair < 2) issue_sub(x, b, cb + 48, cg, rr0, r, rr2, p4, fB);
    }
    barrier_lds_only();   // the ONLY data barrier

    // ---- MFMA phase: all 3 pairs in one run
    floatx4 acc[3][4];
#pragma unroll
    for (int i = 0; i < 3; ++i)
#pragma unroll
        for (int j = 0; j < 4; ++j) acc[i][j] = (floatx4){0.f, 0.f, 0.f, 0.f};

#pragma unroll
    for (int pair = 0; pair < 3; ++pair) {
        // K=32; kg>>1 picks sub-buffer of the pair, kg&1 picks 16B half-row
        const unsigned qbase = (unsigned)(pair * 2 + (kg >> 1)) * HSBUF;
        bf16x8 bfr[4];
#pragma unroll
        for (int nf = 0; nf < 4; ++nf) {
            const int pxv = pxbase + nf * 16 + ln;
            const unsigned boff = (unsigned)((pxv * HSROW + (kg & 1) * 16) ^
                                             (((pxv >> 2) & 7) << 4));
            bfr[nf] = *(const bf16x8*)(hsb + qbase + boff);
        }
#pragma unroll
        for (int mf = 0; mf < 3; ++mf)
#pragma unroll
            for (int nf = 0; nf < 4; ++nf)
                acc[mf][nf] = __builtin_amdgcn_mfma_f32_16x16x32_bf16(
                    af[pair][mf], bfr[nf], acc[mf][nf], 0, 0, 0);
    }

    // epilogue: bias + gate, coalesced 64B segments
#pragma unroll
    for (int mf = 0; mf < 3; ++mf) {
#pragma unroll
        for (int rr = 0; rr < 4; ++rr) {
            const int co = cobase + mf * 16 + kg * 4 + rr;
            const float bias = pw_b[e * DIM + co];
            float* orow = out + ((size_t)(b * DIM + co) * HH + r) * WW;
#pragma unroll
            for (int nf = 0; nf < 4; ++nf)
                orow[pxbase + nf * 16 + ln] = (acc[mf][nf][rr] + bias) * g;
        }
    }
}

extern "C" void kernel_launch(void* const* d_in, const int* in_sizes, int n_in,
                              void* d_out, int out_size, void* d_ws, size_t ws_size,
                              hipStream_t stream) {
    const float* x    = (const float*)d_in[0];
    const float* dw_w = (const float*)d_in[1];
    const float* dw_b = (const float*)d_in[2];
    const float* pw_w = (const float*)d_in[3];
    const float* pw_b = (const float*)d_in[4];
    const float* rw   = (const float*)d_in[5];
    const float* rb   = (const float*)d_in[6];
    float* out = (float*)d_out;

    float* pooled = (float*)d_ws;              // B*C floats

    pool_kernel<<<BB * DIM, 256, 0, stream>>>(x, pooled);
    moe_main<<<HH * BB, 256, 0, stream>>>(x, dw_w, dw_b, pw_w, pw_b,
                                          pooled, rw, rb, out);
}

// Round 21
// 66.926 us; speedup vs baseline: 1.0241x; 1.0241x over previous
//
#include <hip/hip_runtime.h>
#include <math.h>

#define DIM 96
#define NE 4
#define HH 128
#define WW 128
#define BB 16
#define KP 24   // u16 per hs row: 48 B
#define HSROW (KP * 2)           // 48 B
#define HSBUF (WW * HSROW)       // 6144 B per sub-buffer

typedef __attribute__((ext_vector_type(8))) __bf16 bf16x8;
typedef __attribute__((ext_vector_type(2))) __bf16 bf16x2;
typedef __attribute__((ext_vector_type(4))) float floatx4;

// 2x f32 -> packed bf16x2 (compiler emits v_cvt_pk_bf16_f32, RNE)
__device__ __forceinline__ unsigned pack2(float a, float b) {
    bf16x2 v;
    v.x = (__bf16)a;
    v.y = (__bf16)b;
    return __builtin_bit_cast(unsigned, v);
}

// lane N <- lane N-1 (shfl_up 1), pure-VALU DPP (wf_shr:1), OOB lanes -> 0
__device__ __forceinline__ float dpp_up1(float v) {
    return __builtin_bit_cast(float, __builtin_amdgcn_mov_dpp(
        __builtin_bit_cast(int, v), 0x138, 0xF, 0xF, true));
}
// lane N <- lane N+1 (shfl_down 1), DPP (wf_shl:1)
__device__ __forceinline__ float dpp_down1(float v) {
    return __builtin_bit_cast(float, __builtin_amdgcn_mov_dpp(
        __builtin_bit_cast(int, v), 0x130, 0xF, 0xF, true));
}

// LDS-only barrier: make ds_writes visible, rendezvous, but do NOT drain
// vmcnt -- in-flight global prefetches survive the barrier (T4 pattern).
__device__ __forceinline__ void barrier_lds_only() {
    asm volatile("s_waitcnt lgkmcnt(0)" ::: "memory");
    __builtin_amdgcn_s_barrier();
}

// exact-erf GELU via Abramowitz-Stegun 7.1.26 (|eps| <= 1.5e-7), branchless
__device__ __forceinline__ float gelu_erf(float h) {
    const float x = h * 0.70710678118654752f;
    const float a = fabsf(x);
    const float t = __builtin_amdgcn_rcpf(__builtin_fmaf(0.3275911f, a, 1.0f));
    float p = __builtin_fmaf(1.061405429f, t, -1.453152027f);
    p = __builtin_fmaf(p, t, 1.421413741f);
    p = __builtin_fmaf(p, t, -0.284496736f);
    p = __builtin_fmaf(p, t, 0.254829592f);
    p *= t;
    const float e = __expf(-x * x);
    float erfv = __builtin_fmaf(-p, e, 1.0f);
    erfv = copysignf(erfv, x);
    return 0.5f * h * (1.0f + erfv);
}

// ---------------- Kernel A: per-(b,c) mean pool ----------------
__global__ __launch_bounds__(256) void pool_kernel(const float* __restrict__ x,
                                                   float* __restrict__ pooled) {
    const int bc = blockIdx.x;
    const float4* p = (const float4*)(x + (size_t)bc * (HH * WW));
    const int t = threadIdx.x;
    float s = 0.f;
#pragma unroll
    for (int k = 0; k < (HH * WW / 4) / 256; ++k) {
        float4 v = p[t + k * 256];
        s += v.x + v.y + v.z + v.w;
    }
#pragma unroll
    for (int off = 32; off; off >>= 1) s += __shfl_down(s, off, 64);
    __shared__ float ls[4];
    if ((t & 63) == 0) ls[t >> 6] = s;
    __syncthreads();
    if (t == 0) pooled[bc] = (ls[0] + ls[1] + ls[2] + ls[3]) * (1.0f / (HH * WW));
}

// issue 6 float4 loads (2 ch x 3 rows) for one 16-ch sub-chunk
__device__ __forceinline__ void issue_sub(const float* __restrict__ x, int b,
                                          int cbase, int cg, int rr0, int r,
                                          int rr2, int p4, float4 f[2][3]) {
#pragma unroll
    for (int u = 0; u < 2; ++u) {
        const float* pl = x + (size_t)(b * DIM + cbase + cg * 2 + u) * (HH * WW);
        f[u][0] = *(const float4*)(pl + rr0 * WW + p4);
        f[u][1] = *(const float4*)(pl + r   * WW + p4);
        f[u][2] = *(const float4*)(pl + rr2 * WW + p4);
    }
}

// depthwise taps + GELU from preloaded registers -> swizzled hs writes
__device__ __forceinline__ void compute_sub(const float4 f[2][3],
                                            const float (*dwc)[12], int cb,
                                            int cg, float lmask, float rmask,
                                            unsigned char* hsbuf, int p4,
                                            unsigned swz) {
    float hq[2][4];
#pragma unroll
    for (int u = 0; u < 2; ++u) {
        const int c = cb + cg * 2 + u;
        const float4 wA = *(const float4*)&dwc[c][0];   // q0..q3
        const float4 wB = *(const float4*)&dwc[c][4];   // q4..q7
        const float4 wC = *(const float4*)&dwc[c][8];   // q8, bias
        float h0 = wC.y, h1 = wC.y, h2 = wC.y, h3 = wC.y;
#pragma unroll
        for (int row = 0; row < 3; ++row) {
            const float ta = (row == 0) ? wA.x : ((row == 1) ? wA.w : wB.z);
            const float tb = (row == 0) ? wA.y : ((row == 1) ? wB.x : wB.w);
            const float tc = (row == 0) ? wA.z : ((row == 1) ? wB.y : wC.x);
            const float4 f4 = f[u][row];
            const float vl = dpp_up1(f4.w) * lmask;    // VALU DPP, no LDS pipe
            const float vr = dpp_down1(f4.x) * rmask;
            h0 = __builtin_fmaf(ta, vl,   __builtin_fmaf(tb, f4.x, __builtin_fmaf(tc, f4.y, h0)));
            h1 = __builtin_fmaf(ta, f4.x, __builtin_fmaf(tb, f4.y, __builtin_fmaf(tc, f4.z, h1)));
            h2 = __builtin_fmaf(ta, f4.y, __builtin_fmaf(tb, f4.z, __builtin_fmaf(tc, f4.w, h2)));
            h3 = __builtin_fmaf(ta, f4.z, __builtin_fmaf(tb, f4.w, __builtin_fmaf(tc, vr, h3)));
        }
        hq[u][0] = gelu_erf(h0);
        hq[u][1] = gelu_erf(h1);
        hq[u][2] = gelu_erf(h2);
        hq[u][3] = gelu_erf(h3);
    }
    const unsigned wb0 = (unsigned)(p4 * HSROW + cg * 4);
#pragma unroll
    for (int j = 0; j < 4; ++j) {
        const unsigned off = (wb0 + (unsigned)j * HSROW) ^ swz;
        *(unsigned*)(hsbuf + off) = pack2(hq[0][j], hq[1][j]);
    }
}

// ---------------- Kernel C: fused router + expert ----------------
// 256 threads = 4 waves, 1 row per block, 29 KB LDS. Router in-prologue.
// A-fragments loaded straight from global per pair (L2-hot) and converted
// MID-shadow via v_cvt_pk_bf16_f32. hs double-buffered across PAIRS;
// lgkm-only barriers; DPP halo. Row-sequential XCD mapping.
__global__ __launch_bounds__(256, 3) void moe_main(
    const float* __restrict__ x, const float* __restrict__ dw_w,
    const float* __restrict__ dw_b, const float* __restrict__ pw_w,
    const float* __restrict__ pw_b, const float* __restrict__ pooled,
    const float* __restrict__ rw, const float* __restrict__ rb,
    float* __restrict__ out) {
    __shared__ __align__(16) unsigned char hsb[4 * HSBUF];     // 24 KB
    __shared__ float dwc[DIM][12];                             // 4.6 KB
    __shared__ float lsm[4];                                   // router logits

    const int t = threadIdx.x;
    const unsigned bid = blockIdx.x;      // 0..2047
    const int xcd = bid & 7;
    const int s = bid >> 3;               // 0..255
    const int b = xcd * 2 + (s >> 7);     // 2 images per XCD
    const int r = s & 127;                // rows sequential within XCD

    const int lane = t & 63, w = t >> 6;
    const int wm = w & 1, wn = w >> 1;
    const int ln = lane & 15, kg = lane >> 4;
    const int cobase = wm * 48, pxbase = wn * 64;

    const int g32 = t & 31;        // px group (4 px each)
    const int p4 = g32 * 4;
    const int cg = t >> 5;         // 0..7 channel group (2 ch each)
    const unsigned swz = (unsigned)((g32 & 7) << 4);
    const float lmask = (p4 == 0) ? 0.f : 1.f;
    const float rmask = (p4 == 124) ? 0.f : 1.f;

    const float m0 = (r > 0) ? 1.f : 0.f;
    const float m2 = (r < HH - 1) ? 1.f : 0.f;
    const int rr0 = (r > 0) ? r - 1 : 0;
    const int rr2 = (r < HH - 1) ? r + 1 : HH - 1;

    // prologue: issue pair-0 x prefetch (expert-independent) first
    float4 fA[2][3], fB[2][3];
    issue_sub(x, b, 0, cg, rr0, r, rr2, p4, fA);
    issue_sub(x, b, 16, cg, rr0, r, rr2, p4, fB);

    // ---- fused router: wave w computes expert w's logit
    {
        float part = pooled[b * DIM + lane] * rw[w * DIM + lane];
        if (lane < 32)
            part += pooled[b * DIM + 64 + lane] * rw[w * DIM + 64 + lane];
#pragma unroll
        for (int off = 32; off; off >>= 1) part += __shfl_down(part, off, 64);
        if (lane == 0) lsm[w] = part + rb[w];
    }
    barrier_lds_only();
    int e;
    float g;
    {
        const float l0 = lsm[0], l1 = lsm[1], l2 = lsm[2], l3 = lsm[3];
        float m = l0; int mi = 0;
        if (l1 > m) { m = l1; mi = 1; }
        if (l2 > m) { m = l2; mi = 2; }
        if (l3 > m) { m = l3; mi = 3; }
        const float denom = __expf(l0 - m) + __expf(l1 - m) +
                            __expf(l2 - m) + __expf(l3 - m);
        const float wv = 1.0f / denom;
        g = wv / (wv + 1e-8f);
        e = mi;
    }

    // ---- stage depthwise taps + bias, row-edge masks folded in
    for (int j = t; j < DIM * 12; j += 256) {
        const int c = j / 12, q = j - c * 12;
        float v = 0.f;
        if (q < 9) {
            v = dw_w[((size_t)e * DIM + c) * 9 + q];
            if (q < 3) v *= m0;
            if (q >= 6) v *= m2;
        } else if (q == 9) v = dw_b[e * DIM + c];
        dwc[c][q] = v;
    }
    barrier_lds_only();   // fA/fB prefetches survive

    floatx4 acc[3][4];
#pragma unroll
    for (int i = 0; i < 3; ++i)
#pragma unroll
        for (int j = 0; j < 4; ++j) acc[i][j] = (floatx4){0.f, 0.f, 0.f, 0.f};

#pragma unroll
    for (int pair = 0; pair < 3; ++pair) {
        const int cb = pair * 32;
        unsigned char* h0 = hsb + (unsigned)((pair & 1) * 2) * HSBUF;
        unsigned char* h1 = h0 + HSBUF;
        // issue this pair's A-fragment loads (L2-hot)
        float4 a0[3], a1[3];
#pragma unroll
        for (int mf = 0; mf < 3; ++mf) {
            const float* ap = pw_w + ((size_t)e * DIM + cobase + mf * 16 + ln) * DIM
                              + cb + kg * 8;
            a0[mf] = *(const float4*)ap;
            a1[mf] = *(const float4*)(ap + 4);
        }
        // compute sub0 from in-flight fA, refill fA for next pair
        compute_sub(fA, dwc, cb, cg, lmask, rmask, h0, p4, swz);
        if (pair < 2) issue_sub(x, b, cb + 32, cg, rr0, r, rr2, p4, fA);
        // convert A-fragments mid-shadow: raw a0/a1 die here (short range)
        bf16x8 af[3];
#pragma unroll
        for (int mf = 0; mf < 3; ++mf) {
            uint4 u;
            u.x = pack2(a0[mf].x, a0[mf].y);
            u.y = pack2(a0[mf].z, a0[mf].w);
            u.z = pack2(a1[mf].x, a1[mf].y);
            u.w = pack2(a1[mf].z, a1[mf].w);
            af[mf] = __builtin_bit_cast(bf16x8, u);
        }
        // compute sub1 from in-flight fB, refill fB for next pair
        compute_sub(fB, dwc, cb + 16, cg, lmask, rmask, h1, p4, swz);
        if (pair < 2) issue_sub(x, b, cb + 48, cg, rr0, r, rr2, p4, fB);
        barrier_lds_only();   // hs visible; prefetches stay in flight

        // MFMA: K=32; kg>>1 picks sub-buffer, kg&1 picks 16B half-row
        const unsigned qbase = (unsigned)((pair & 1) * 2 + (kg >> 1)) * HSBUF;
        bf16x8 bfr[4];
#pragma unroll
        for (int nf = 0; nf < 4; ++nf) {
            const int pxv = pxbase + nf * 16 + ln;
            const unsigned boff = (unsigned)((pxv * HSROW + (kg & 1) * 16) ^
                                             (((pxv >> 2) & 7) << 4));
            bfr[nf] = *(const bf16x8*)(hsb + qbase + boff);
        }
#pragma unroll
        for (int mf = 0; mf < 3; ++mf)
#pragma unroll
            for (int nf = 0; nf < 4; ++nf)
                acc[mf][nf] = __builtin_amdgcn_mfma_f32_16x16x32_bf16(
                    af[mf], bfr[nf], acc[mf][nf], 0, 0, 0);
        // no second barrier: next pair writes the OTHER hs buffers
    }

    // epilogue: bias + gate, coalesced 64B segments
#pragma unroll
    for (int mf = 0; mf < 3; ++mf) {
#pragma unroll
        for (int rr = 0; rr < 4; ++rr) {
            const int co = cobase + mf * 16 + kg * 4 + rr;
            const float bias = pw_b[e * DIM + co];
            float* orow = out + ((size_t)(b * DIM + co) * HH + r) * WW;
#pragma unroll
            for (int nf = 0; nf < 4; ++nf)
                orow[pxbase + nf * 16 + ln] = (acc[mf][nf][rr] + bias) * g;
        }
    }
}

extern "C" void kernel_launch(void* const* d_in, const int* in_sizes, int n_in,
                              void* d_out, int out_size, void* d_ws, size_t ws_size,
                              hipStream_t stream) {
    const float* x    = (const float*)d_in[0];
    const float* dw_w = (const float*)d_in[1];
    const float* dw_b = (const float*)d_in[2];
    const float* pw_w = (const float*)d_in[3];
    const float* pw_b = (const float*)d_in[4];
    const float* rw   = (const float*)d_in[5];
    const float* rb   = (const float*)d_in[6];
    float* out = (float*)d_out;

    float* pooled = (float*)d_ws;              // B*C floats

    pool_kernel<<<BB * DIM, 256, 0, stream>>>(x, pooled);
    moe_main<<<HH * BB, 256, 0, stream>>>(x, dw_w, dw_b, pw_w, pw_b,
                                          pooled, rw, rb, out);
}